// Round 12
// baseline (68.690 us; speedup 1.0000x reference)
//
#include <hip/hip_runtime.h>
#include <hip/hip_bf16.h>

#define UNIF 128
#define NH   8
#define HD   16
#define BATCH 4
#define SEQ  2048
#define ROWS (BATCH*SEQ)   // 8192

typedef __attribute__((ext_vector_type(8)))  short bf16x8;
typedef __attribute__((ext_vector_type(16))) float f32x16;
typedef __attribute__((ext_vector_type(4)))  float f32x4;
typedef __attribute__((ext_vector_type(4)))  unsigned uint32x4;
typedef __attribute__((ext_vector_type(2)))  unsigned uint2v;

// round-to-nearest-even f32 -> bf16 (finite inputs)
static __device__ __forceinline__ unsigned f2bf(float x) {
    unsigned u = __builtin_bit_cast(unsigned, x);
    return (u + 0x7fffu + ((u >> 16) & 1u)) >> 16;
}
static __device__ __forceinline__ unsigned pkbf(float a, float b) {
    return f2bf(a) | (f2bf(b) << 16);
}
static __device__ __forceinline__ unsigned short bfs(float x) {
    return (unsigned short)f2bf(x);
}
// HW packed f32x2 -> bf16x2, 1 VALU op
static __device__ __forceinline__ unsigned cvtpk(float a, float b) {
    unsigned r;
    asm("v_cvt_pk_bf16_f32 %0, %1, %2" : "=v"(r) : "v"(a), "v"(b));
    return r;
}
// verified-good builtin (round 6): both outputs consumed explicitly
static __device__ __forceinline__ void plswap(unsigned &a, unsigned &b) {
    uint2v r = __builtin_amdgcn_permlane32_swap(a, b, false, false);
    a = r[0]; b = r[1];
}
// 8 fp32 -> bf16x8 fragment (4 cvt_pk)
static __device__ __forceinline__ bf16x8 ld8f(const float* p) {
    const float4 x = *(const float4*)p;
    const float4 y = *(const float4*)(p + 4);
    uint32x4 u = { cvtpk(x.x, x.y), cvtpk(x.z, x.w),
                   cvtpk(y.x, y.y), cvtpk(y.z, y.w) };
    return __builtin_bit_cast(bf16x8, u);
}

// ---------------- Kernel 0: prep — coalesced W transposes (4 blocks) --------
// Block m transposes one 128x128 matrix via LDS (+1 pad, conflict-free).
__global__ __launch_bounds__(256) void prep_kernel(
    const float* __restrict__ Wq, const float* __restrict__ Wk,
    const float* __restrict__ Wv, const float* __restrict__ Wo,
    unsigned short* __restrict__ Wqt, unsigned short* __restrict__ Wkt,
    unsigned short* __restrict__ Wvt, unsigned short* __restrict__ Wot)
{
    __shared__ float L[UNIF][UNIF + 1];   // 66 KB
    const int m = blockIdx.x;
    const float* src = (m==0)?Wq:(m==1)?Wk:(m==2)?Wv:Wo;
    unsigned short* dst = (m==0)?Wqt:(m==1)?Wkt:(m==2)?Wvt:Wot;
    const float qsc = 0.25f * 1.4426950408889634f;   // 1/sqrt(16)*log2e into Wq

    for (int t = threadIdx.x; t < UNIF*UNIF/4; t += 256) {
        const float4 v = ((const float4*)src)[t];
        const int row = t >> 5, col = (t & 31) * 4;
        L[row][col] = v.x; L[row][col+1] = v.y; L[row][col+2] = v.z; L[row][col+3] = v.w;
    }
    __syncthreads();

    for (int t = threadIdx.x; t < UNIF*UNIF; t += 256) {
        const int r = t >> 7, s = t & 127;   // dst[r][s], s fastest -> coalesced
        float val;
        if (m == 0)      val = L[s][r] * qsc;                    // Wqt[c][k]
        else if (m == 1) val = L[s][r];                          // Wkt[c][k]
        else if (m == 2) val = L[s][(r & 15)*NH + (r >> 4)];     // Wvt[c][k]
        else             val = L[(s & 15)*NH + (s >> 4)][r];     // Wot[o][c]
        dst[r*UNIF + s] = bfs(val);
    }
}

// ---------------- Kernel A: merged QKV projection (vec read once) -----------
// grid ROWS/32 = 256 blocks, 256 threads. Wave w: Q,K rows (w&1)*16, cols
// (w>>1)*64; V cols [w*32,w*32+32) over all 32 rows.
__global__ __launch_bounds__(256) void proj_kernel(
    const float* __restrict__ vec,  const unsigned short* __restrict__ Wqt,
    const unsigned short* __restrict__ Wkt, const unsigned short* __restrict__ Wvt,
    unsigned short* __restrict__ Qbf, unsigned short* __restrict__ Kbf,
    unsigned short* __restrict__ Vt)
{
    const int row0 = blockIdx.x * 32;
    const int b    = row0 >> 11;
    const int n0   = row0 & (SEQ-1);
    const int lane = threadIdx.x & 63;
    const int w    = threadIdx.x >> 6;
    const int l15  = lane & 15, g = lane >> 4;
    const int rh   = w & 1, ch = w >> 1;
    const f32x4 Z4 = {0.f,0.f,0.f,0.f};

    // both 16-row halves of vec as bf16 fragments (L1-shared across waves)
    bf16x8 a[2][4];
    #pragma unroll
    for (int u = 0; u < 2; ++u)
        #pragma unroll
        for (int t = 0; t < 4; ++t)
            a[u][t] = ld8f(vec + (size_t)(row0 + 16*u + l15)*UNIF + 32*t + 8*g);

    // ---- Q and K: rows rh*16.., cols ch*64.. ----
    #pragma unroll
    for (int mqk = 0; mqk < 2; ++mqk) {
        const unsigned short* Wt = mqk ? Wkt : Wqt;
        unsigned short* dst = mqk ? Kbf : Qbf;
        #pragma unroll
        for (int j = 0; j < 4; ++j) {
            const int ctile = ch*64 + 16*j;
            f32x4 acc = Z4;
            #pragma unroll
            for (int t = 0; t < 4; ++t) {
                const bf16x8 bfr = *(const bf16x8*)(Wt + (size_t)(ctile + l15)*UNIF + 32*t + 8*g);
                acc = __builtin_amdgcn_mfma_f32_16x16x32_bf16(a[rh][t], bfr, acc, 0, 0, 0);
            }
            const int h = ctile >> 4;
            #pragma unroll
            for (int r = 0; r < 4; ++r)
                dst[((size_t)(b*NH + h)*SEQ + n0 + rh*16 + 4*g + r)*HD + l15] = bfs(acc[r]);
        }
    }

    // ---- V (transposed store): cols w*32..w*32+32, both row halves ----
    #pragma unroll
    for (int jj = 0; jj < 2; ++jj) {
        const int c0 = w*32 + 16*jj;
        bf16x8 av[4];
        #pragma unroll
        for (int t = 0; t < 4; ++t)
            av[t] = *(const bf16x8*)(Wvt + (size_t)(c0 + l15)*UNIF + 32*t + 8*g);
        #pragma unroll
        for (int u = 0; u < 2; ++u) {
            f32x4 acc = Z4;
            #pragma unroll
            for (int t = 0; t < 4; ++t)
                acc = __builtin_amdgcn_mfma_f32_16x16x32_bf16(av[t], a[u][t], acc, 0, 0, 0);
            #pragma unroll
            for (int r = 0; r < 4; ++r) {
                const int c = c0 + 4*g + r;
                const int h = c >> 4, d = c & 15;
                Vt[((size_t)(b*NH + h)*HD + d)*SEQ + n0 + 16*u + l15] = bfs(acc[r]);
            }
        }
    }
}

// ---------------- Kernel B: MFMA attention ((256,3) + setprio) --------------
__global__ __launch_bounds__(256, 3) void attn_kernel(
    const unsigned short* __restrict__ Qbf, const unsigned short* __restrict__ Kbf,
    const unsigned short* __restrict__ Vt, unsigned short* __restrict__ rb)
{
    __shared__ float Obuf[2][2][2][9][32];   // [itile][buf][hi][reg][i] 18 KB

    const int lane = threadIdx.x & 63;
    const int w    = threadIdx.x >> 6;    // j-quarter
    const int bh   = blockIdx.y;
    const int i0   = blockIdx.x * 64;
    const int l31  = lane & 31, hi = lane >> 5;

    const bf16x8 qA = *(const bf16x8*)(Qbf + ((size_t)bh*SEQ + i0      + l31)*HD + 8*hi);
    const bf16x8 qC = *(const bf16x8*)(Qbf + ((size_t)bh*SEQ + i0 + 32 + l31)*HD + 8*hi);
    const unsigned short* kp   = Kbf + (size_t)bh*SEQ*HD + ((size_t)(w*(SEQ/4) + l31))*HD + 8*hi;
    const unsigned short* vrow = Vt  + ((size_t)bh*HD + l31)*SEQ + w*(SEQ/4);  // deref only l31<16

    const unsigned ov = (l31 == 16 || l31 == 20) ? 0x3F803F80u : 0u;
    const uint32x4 ac4 = {ov, ov, ov, ov};
    const bf16x8 acst = __builtin_bit_cast(bf16x8, ac4);

    f32x16 OA = {0.f,0.f,0.f,0.f,0.f,0.f,0.f,0.f,0.f,0.f,0.f,0.f,0.f,0.f,0.f,0.f};
    f32x16 OC = OA;
    const f32x16 Zero = OA;

    auto process = [&](const bf16x8& qB, const bf16x8& kA,
                       const bf16x8& av0, const bf16x8& av1, f32x16& O) {
        __builtin_amdgcn_s_setprio(1);
        f32x16 S = __builtin_amdgcn_mfma_f32_32x32x16_bf16(kA, qB, Zero, 0, 0, 0);
        __builtin_amdgcn_s_setprio(0);
        unsigned W0[4], W1[4];
        #pragma unroll
        for (int c = 0; c < 4; ++c) {
            W0[c] = cvtpk(__builtin_amdgcn_exp2f(S[4*c+0]), __builtin_amdgcn_exp2f(S[4*c+1]));
            W1[c] = cvtpk(__builtin_amdgcn_exp2f(S[4*c+2]), __builtin_amdgcn_exp2f(S[4*c+3]));
        }
        plswap(W0[0], W0[1]);  plswap(W1[0], W1[1]);
        plswap(W0[2], W0[3]);  plswap(W1[2], W1[3]);
        const uint32x4 fa = {W0[0], W1[0], W0[1], W1[1]};
        const uint32x4 fb = {W0[2], W1[2], W0[3], W1[3]};
        __builtin_amdgcn_s_setprio(1);
        O = __builtin_amdgcn_mfma_f32_32x32x16_bf16(av0, __builtin_bit_cast(bf16x8, fa), O, 0, 0, 0);
        O = __builtin_amdgcn_mfma_f32_32x32x16_bf16(av1, __builtin_bit_cast(bf16x8, fb), O, 0, 0, 0);
        __builtin_amdgcn_s_setprio(0);
    };

    constexpr int NT = (SEQ/4)/32;   // 16 j-tiles per wave
    #pragma unroll 1
    for (int t = 0; t < NT; ++t) {
        const bf16x8 kA = *(const bf16x8*)(kp + (size_t)t*32*HD);
        bf16x8 av0 = acst, av1 = acst;
        if (l31 < 16) {
            av0 = *(const bf16x8*)(vrow + t*32 + 8*hi);
            av1 = *(const bf16x8*)(vrow + t*32 + 16 + 8*hi);
        }
        process(qA, kA, av0, av1, OA);
        process(qC, kA, av0, av1, OC);
    }

    // ---- merge 4 j-quarters per i-tile ----
    const int buf = w >> 1;
    if (w & 1) {
        #pragma unroll
        for (int r = 0; r < 9; ++r) {
            Obuf[0][buf][hi][r][l31] = OA[r];
            Obuf[1][buf][hi][r][l31] = OC[r];
        }
    }
    __syncthreads();
    if (!(w & 1)) {
        #pragma unroll
        for (int r = 0; r < 9; ++r) {
            OA[r] += Obuf[0][buf][hi][r][l31];
            OC[r] += Obuf[1][buf][hi][r][l31];
        }
        if (w == 2) {
            #pragma unroll
            for (int r = 0; r < 9; ++r) {
                Obuf[0][1][hi][r][l31] = OA[r];
                Obuf[1][1][hi][r][l31] = OC[r];
            }
        }
    }
    __syncthreads();
    if (w == 0) {
        #pragma unroll
        for (int r = 0; r < 9; ++r) {
            OA[r] += Obuf[0][1][hi][r][l31];
            OC[r] += Obuf[1][1][hi][r][l31];
        }
        const int b = bh >> 3, h = bh & 7;
        #pragma unroll
        for (int it = 0; it < 2; ++it) {
            const f32x16& O = it ? OC : OA;
            const float inv = 1.f / O[8];
            const unsigned a0 = pkbf(O[0]*inv, O[1]*inv);
            const unsigned a1 = pkbf(O[2]*inv, O[3]*inv);
            const unsigned a2 = pkbf(O[4]*inv, O[5]*inv);
            const unsigned a3 = pkbf(O[6]*inv, O[7]*inv);
            unsigned short* base = rb + ((size_t)b*SEQ + i0 + it*32 + l31)*UNIF + h*HD + hi*4;
            uint2 u01; u01.x = a0; u01.y = a1;
            uint2 u23; u23.x = a2; u23.y = a3;
            *(uint2*)(base)     = u01;
            *(uint2*)(base + 8) = u23;
        }
    }
}

// ---------------- Kernel C: output projection (fatter blocks) ---------------
// grid ROWS/32 = 256, block 256. Wave w: rows (w&1)*16, cols (w>>1)*64;
// A-fragments loaded once, reused across 4 col-tiles.
__global__ __launch_bounds__(256) void out_kernel(
    const unsigned short* __restrict__ rb, const unsigned short* __restrict__ Wot,
    float* __restrict__ out)
{
    const int row0 = blockIdx.x * 32;
    const int lane = threadIdx.x & 63;
    const int w    = threadIdx.x >> 6;
    const int l15  = lane & 15, g = lane >> 4;
    const int rw   = row0 + (w & 1)*16;
    const int oc0  = (w >> 1)*64;
    const f32x4 Z4 = {0.f,0.f,0.f,0.f};

    bf16x8 a[4];
    #pragma unroll
    for (int t = 0; t < 4; ++t)
        a[t] = *(const bf16x8*)(rb + (size_t)(rw + l15)*UNIF + 32*t + 8*g);

    #pragma unroll
    for (int j = 0; j < 4; ++j) {
        const int oc = oc0 + 16*j;
        f32x4 acc = Z4;
        #pragma unroll
        for (int t = 0; t < 4; ++t) {
            const bf16x8 bfr = *(const bf16x8*)(Wot + (size_t)(oc + l15)*UNIF + 32*t + 8*g);
            acc = __builtin_amdgcn_mfma_f32_16x16x32_bf16(a[t], bfr, acc, 0, 0, 0);
        }
        #pragma unroll
        for (int r = 0; r < 4; ++r)
            out[(size_t)(rw + 4*g + r)*UNIF + oc + l15] = acc[r];
    }
}

extern "C" void kernel_launch(void* const* d_in, const int* in_sizes, int n_in,
                              void* d_out, int out_size, void* d_ws, size_t ws_size,
                              hipStream_t stream) {
    const float* Wq  = (const float*)d_in[0];
    const float* Wk  = (const float*)d_in[1];
    const float* Wv  = (const float*)d_in[2];
    const float* Wo  = (const float*)d_in[3];
    const float* vec = (const float*)d_in[4];
    float* out = (float*)d_out;

    const size_t tsz = (size_t)BATCH*NH*SEQ*HD;
    unsigned short* Wqt = (unsigned short*)d_ws;
    unsigned short* Wkt = Wqt + UNIF*UNIF;
    unsigned short* Wvt = Wkt + UNIF*UNIF;
    unsigned short* Wot = Wvt + UNIF*UNIF;
    unsigned short* Qbf = Wot + UNIF*UNIF;
    unsigned short* Kbf = Qbf + tsz;
    unsigned short* Vt  = Kbf + tsz;
    unsigned short* rb  = Vt  + tsz;

    prep_kernel<<<4, 256, 0, stream>>>(Wq, Wk, Wv, Wo, Wqt, Wkt, Wvt, Wot);
    proj_kernel<<<ROWS/32, 256, 0, stream>>>(vec, Wqt, Wkt, Wvt, Qbf, Kbf, Vt);
    attn_kernel<<<dim3(SEQ/64, BATCH*NH), 256, 0, stream>>>(Qbf, Kbf, Vt, rb);
    out_kernel<<<ROWS/32, 256, 0, stream>>>(rb, Wot, out);
}

// Round 13
// 59.390 us; speedup vs baseline: 1.1566x; 1.1566x over previous
//
#include <hip/hip_runtime.h>
#include <hip/hip_bf16.h>

#define UNIF 128
#define NH   8
#define HD   16
#define BATCH 4
#define SEQ  2048
#define ROWS (BATCH*SEQ)   // 8192

typedef __attribute__((ext_vector_type(8)))  short bf16x8;
typedef __attribute__((ext_vector_type(16))) float f32x16;
typedef __attribute__((ext_vector_type(4)))  float f32x4;
typedef __attribute__((ext_vector_type(4)))  unsigned uint32x4;
typedef __attribute__((ext_vector_type(2)))  unsigned uint2v;

// round-to-nearest-even f32 -> bf16 (finite inputs)
static __device__ __forceinline__ unsigned f2bf(float x) {
    unsigned u = __builtin_bit_cast(unsigned, x);
    return (u + 0x7fffu + ((u >> 16) & 1u)) >> 16;
}
static __device__ __forceinline__ unsigned pkbf(float a, float b) {
    return f2bf(a) | (f2bf(b) << 16);
}
static __device__ __forceinline__ unsigned short bfs(float x) {
    return (unsigned short)f2bf(x);
}
// HW packed f32x2 -> bf16x2, 1 VALU op
static __device__ __forceinline__ unsigned cvtpk(float a, float b) {
    unsigned r;
    asm("v_cvt_pk_bf16_f32 %0, %1, %2" : "=v"(r) : "v"(a), "v"(b));
    return r;
}
// verified-good builtin (round 6): both outputs consumed explicitly
static __device__ __forceinline__ void plswap(unsigned &a, unsigned &b) {
    uint2v r = __builtin_amdgcn_permlane32_swap(a, b, false, false);
    a = r[0]; b = r[1];
}
// 8 fp32 -> bf16x8 fragment (4 cvt_pk)
static __device__ __forceinline__ bf16x8 ld8f(const float* p) {
    const float4 x = *(const float4*)p;
    const float4 y = *(const float4*)(p + 4);
    uint32x4 u = { cvtpk(x.x, x.y), cvtpk(x.z, x.w),
                   cvtpk(y.x, y.y), cvtpk(y.z, y.w) };
    return __builtin_bit_cast(bf16x8, u);
}

// ---------------- Kernel 0: prep — coalesced W transposes (4 blocks) --------
__global__ __launch_bounds__(256) void prep_kernel(
    const float* __restrict__ Wq, const float* __restrict__ Wk,
    const float* __restrict__ Wv, const float* __restrict__ Wo,
    unsigned short* __restrict__ Wqt, unsigned short* __restrict__ Wkt,
    unsigned short* __restrict__ Wvt, unsigned short* __restrict__ Wot)
{
    __shared__ float L[UNIF][UNIF + 1];   // 66 KB
    const int m = blockIdx.x;
    const float* src = (m==0)?Wq:(m==1)?Wk:(m==2)?Wv:Wo;
    unsigned short* dst = (m==0)?Wqt:(m==1)?Wkt:(m==2)?Wvt:Wot;
    const float qsc = 0.25f * 1.4426950408889634f;   // 1/sqrt(16)*log2e into Wq

    for (int t = threadIdx.x; t < UNIF*UNIF/4; t += 256) {
        const float4 v = ((const float4*)src)[t];
        const int row = t >> 5, col = (t & 31) * 4;
        L[row][col] = v.x; L[row][col+1] = v.y; L[row][col+2] = v.z; L[row][col+3] = v.w;
    }
    __syncthreads();

    for (int t = threadIdx.x; t < UNIF*UNIF; t += 256) {
        const int r = t >> 7, s = t & 127;   // dst[r][s], s fastest -> coalesced
        float val;
        if (m == 0)      val = L[s][r] * qsc;                    // Wqt[c][k]
        else if (m == 1) val = L[s][r];                          // Wkt[c][k]
        else if (m == 2) val = L[s][(r & 15)*NH + (r >> 4)];     // Wvt[c][k]
        else             val = L[(s & 15)*NH + (s >> 4)][r];     // Wot[o][c]
        dst[r*UNIF + s] = bfs(val);
    }
}

// ---------------- Kernel A: QKV projection, sel-split, 16 rows/block --------
// grid (ROWS/16, 3) = 1536 blocks (6 waves/SIMD). Wave w: cols w*32..w*32+31.
__global__ __launch_bounds__(256) void proj_kernel(
    const float* __restrict__ vec,  const unsigned short* __restrict__ Wqt,
    const unsigned short* __restrict__ Wkt, const unsigned short* __restrict__ Wvt,
    unsigned short* __restrict__ Qbf, unsigned short* __restrict__ Kbf,
    unsigned short* __restrict__ Vt)
{
    const int sel  = blockIdx.y;
    const int row0 = blockIdx.x * 16;
    const int b    = row0 >> 11;
    const int n0   = row0 & (SEQ-1);
    const int lane = threadIdx.x & 63;
    const int w    = threadIdx.x >> 6;
    const int l15  = lane & 15, g = lane >> 4;
    const f32x4 Z4 = {0.f,0.f,0.f,0.f};

    // 16 vec rows as bf16 A/B fragments (shared pattern for all sels)
    bf16x8 a[4];
    #pragma unroll
    for (int t = 0; t < 4; ++t)
        a[t] = ld8f(vec + (size_t)(row0 + l15)*UNIF + 32*t + 8*g);

    if (sel < 2) {
        const unsigned short* Wt = sel ? Wkt : Wqt;
        unsigned short* dst = sel ? Kbf : Qbf;
        #pragma unroll
        for (int j = 0; j < 2; ++j) {
            const int ctile = w*32 + 16*j;
            f32x4 acc = Z4;
            #pragma unroll
            for (int t = 0; t < 4; ++t) {
                const bf16x8 bfr = *(const bf16x8*)(Wt + (size_t)(ctile + l15)*UNIF + 32*t + 8*g);
                acc = __builtin_amdgcn_mfma_f32_16x16x32_bf16(a[t], bfr, acc, 0, 0, 0);
            }
            const int h = ctile >> 4;
            #pragma unroll
            for (int r = 0; r < 4; ++r)
                dst[((size_t)(b*NH + h)*SEQ + n0 + 4*g + r)*HD + l15] = bfs(acc[r]);
        }
    } else {
        // swapped: D[c][n]; A = Wvt rows (c), B = vec rows (n)
        #pragma unroll
        for (int j = 0; j < 2; ++j) {
            const int c0 = w*32 + 16*j;
            f32x4 acc = Z4;
            #pragma unroll
            for (int t = 0; t < 4; ++t) {
                const bf16x8 av = *(const bf16x8*)(Wvt + (size_t)(c0 + l15)*UNIF + 32*t + 8*g);
                acc = __builtin_amdgcn_mfma_f32_16x16x32_bf16(av, a[t], acc, 0, 0, 0);
            }
            #pragma unroll
            for (int r = 0; r < 4; ++r) {
                const int c = c0 + 4*g + r;
                const int h = c >> 4, d = c & 15;
                Vt[((size_t)(b*NH + h)*HD + d)*SEQ + n0 + l15] = bfs(acc[r]);
            }
        }
    }
}

// ---------------- Kernel B: MFMA attention ((256,3) + setprio) --------------
__global__ __launch_bounds__(256, 3) void attn_kernel(
    const unsigned short* __restrict__ Qbf, const unsigned short* __restrict__ Kbf,
    const unsigned short* __restrict__ Vt, unsigned short* __restrict__ rb)
{
    __shared__ float Obuf[2][2][2][9][32];   // [itile][buf][hi][reg][i] 18 KB

    const int lane = threadIdx.x & 63;
    const int w    = threadIdx.x >> 6;    // j-quarter
    const int bh   = blockIdx.y;
    const int i0   = blockIdx.x * 64;
    const int l31  = lane & 31, hi = lane >> 5;

    const bf16x8 qA = *(const bf16x8*)(Qbf + ((size_t)bh*SEQ + i0      + l31)*HD + 8*hi);
    const bf16x8 qC = *(const bf16x8*)(Qbf + ((size_t)bh*SEQ + i0 + 32 + l31)*HD + 8*hi);
    const unsigned short* kp   = Kbf + (size_t)bh*SEQ*HD + ((size_t)(w*(SEQ/4) + l31))*HD + 8*hi;
    const unsigned short* vrow = Vt  + ((size_t)bh*HD + l31)*SEQ + w*(SEQ/4);  // deref only l31<16

    const unsigned ov = (l31 == 16 || l31 == 20) ? 0x3F803F80u : 0u;
    const uint32x4 ac4 = {ov, ov, ov, ov};
    const bf16x8 acst = __builtin_bit_cast(bf16x8, ac4);

    f32x16 OA = {0.f,0.f,0.f,0.f,0.f,0.f,0.f,0.f,0.f,0.f,0.f,0.f,0.f,0.f,0.f,0.f};
    f32x16 OC = OA;
    const f32x16 Zero = OA;

    auto process = [&](const bf16x8& qB, const bf16x8& kA,
                       const bf16x8& av0, const bf16x8& av1, f32x16& O) {
        __builtin_amdgcn_s_setprio(1);
        f32x16 S = __builtin_amdgcn_mfma_f32_32x32x16_bf16(kA, qB, Zero, 0, 0, 0);
        __builtin_amdgcn_s_setprio(0);
        unsigned W0[4], W1[4];
        #pragma unroll
        for (int c = 0; c < 4; ++c) {
            W0[c] = cvtpk(__builtin_amdgcn_exp2f(S[4*c+0]), __builtin_amdgcn_exp2f(S[4*c+1]));
            W1[c] = cvtpk(__builtin_amdgcn_exp2f(S[4*c+2]), __builtin_amdgcn_exp2f(S[4*c+3]));
        }
        plswap(W0[0], W0[1]);  plswap(W1[0], W1[1]);
        plswap(W0[2], W0[3]);  plswap(W1[2], W1[3]);
        const uint32x4 fa = {W0[0], W1[0], W0[1], W1[1]};
        const uint32x4 fb = {W0[2], W1[2], W0[3], W1[3]};
        __builtin_amdgcn_s_setprio(1);
        O = __builtin_amdgcn_mfma_f32_32x32x16_bf16(av0, __builtin_bit_cast(bf16x8, fa), O, 0, 0, 0);
        O = __builtin_amdgcn_mfma_f32_32x32x16_bf16(av1, __builtin_bit_cast(bf16x8, fb), O, 0, 0, 0);
        __builtin_amdgcn_s_setprio(0);
    };

    constexpr int NT = (SEQ/4)/32;   // 16 j-tiles per wave
    #pragma unroll 1
    for (int t = 0; t < NT; ++t) {
        const bf16x8 kA = *(const bf16x8*)(kp + (size_t)t*32*HD);
        bf16x8 av0 = acst, av1 = acst;
        if (l31 < 16) {
            av0 = *(const bf16x8*)(vrow + t*32 + 8*hi);
            av1 = *(const bf16x8*)(vrow + t*32 + 16 + 8*hi);
        }
        process(qA, kA, av0, av1, OA);
        process(qC, kA, av0, av1, OC);
    }

    // ---- merge 4 j-quarters per i-tile ----
    const int buf = w >> 1;
    if (w & 1) {
        #pragma unroll
        for (int r = 0; r < 9; ++r) {
            Obuf[0][buf][hi][r][l31] = OA[r];
            Obuf[1][buf][hi][r][l31] = OC[r];
        }
    }
    __syncthreads();
    if (!(w & 1)) {
        #pragma unroll
        for (int r = 0; r < 9; ++r) {
            OA[r] += Obuf[0][buf][hi][r][l31];
            OC[r] += Obuf[1][buf][hi][r][l31];
        }
        if (w == 2) {
            #pragma unroll
            for (int r = 0; r < 9; ++r) {
                Obuf[0][1][hi][r][l31] = OA[r];
                Obuf[1][1][hi][r][l31] = OC[r];
            }
        }
    }
    __syncthreads();
    if (w == 0) {
        #pragma unroll
        for (int r = 0; r < 9; ++r) {
            OA[r] += Obuf[0][1][hi][r][l31];
            OC[r] += Obuf[1][1][hi][r][l31];
        }
        const int b = bh >> 3, h = bh & 7;
        #pragma unroll
        for (int it = 0; it < 2; ++it) {
            const f32x16& O = it ? OC : OA;
            const float inv = 1.f / O[8];
            const unsigned a0 = pkbf(O[0]*inv, O[1]*inv);
            const unsigned a1 = pkbf(O[2]*inv, O[3]*inv);
            const unsigned a2 = pkbf(O[4]*inv, O[5]*inv);
            const unsigned a3 = pkbf(O[6]*inv, O[7]*inv);
            unsigned short* base = rb + ((size_t)b*SEQ + i0 + it*32 + l31)*UNIF + h*HD + hi*4;
            uint2 u01; u01.x = a0; u01.y = a1;
            uint2 u23; u23.x = a2; u23.y = a3;
            *(uint2*)(base)     = u01;
            *(uint2*)(base + 8) = u23;
        }
    }
}

// ---------------- Kernel C: output projection (1024 blocks, round-10) -------
__global__ __launch_bounds__(256) void out_kernel(
    const unsigned short* __restrict__ rb, const unsigned short* __restrict__ Wot,
    float* __restrict__ out)
{
    const int row0 = blockIdx.x * 32;
    const int lane = threadIdx.x & 63;
    const int w    = threadIdx.x >> 6;
    const int l15  = lane & 15, g = lane >> 4;
    const int rw   = row0 + (w & 1)*16;
    const int oc   = blockIdx.y*32 + (w >> 1)*16;
    const f32x4 Z4 = {0.f,0.f,0.f,0.f};

    bf16x8 a[4];
    #pragma unroll
    for (int t = 0; t < 4; ++t)
        a[t] = *(const bf16x8*)(rb + (size_t)(rw + l15)*UNIF + 32*t + 8*g);

    f32x4 acc = Z4;
    #pragma unroll
    for (int t = 0; t < 4; ++t) {
        const bf16x8 bfr = *(const bf16x8*)(Wot + (size_t)(oc + l15)*UNIF + 32*t + 8*g);
        acc = __builtin_amdgcn_mfma_f32_16x16x32_bf16(a[t], bfr, acc, 0, 0, 0);
    }
    #pragma unroll
    for (int r = 0; r < 4; ++r)
        out[(size_t)(rw + 4*g + r)*UNIF + oc + l15] = acc[r];
}

extern "C" void kernel_launch(void* const* d_in, const int* in_sizes, int n_in,
                              void* d_out, int out_size, void* d_ws, size_t ws_size,
                              hipStream_t stream) {
    const float* Wq  = (const float*)d_in[0];
    const float* Wk  = (const float*)d_in[1];
    const float* Wv  = (const float*)d_in[2];
    const float* Wo  = (const float*)d_in[3];
    const float* vec = (const float*)d_in[4];
    float* out = (float*)d_out;

    const size_t tsz = (size_t)BATCH*NH*SEQ*HD;
    unsigned short* Wqt = (unsigned short*)d_ws;
    unsigned short* Wkt = Wqt + UNIF*UNIF;
    unsigned short* Wvt = Wkt + UNIF*UNIF;
    unsigned short* Wot = Wvt + UNIF*UNIF;
    unsigned short* Qbf = Wot + UNIF*UNIF;
    unsigned short* Kbf = Qbf + tsz;
    unsigned short* Vt  = Kbf + tsz;
    unsigned short* rb  = Vt  + tsz;

    prep_kernel<<<4, 256, 0, stream>>>(Wq, Wk, Wv, Wo, Wqt, Wkt, Wvt, Wot);
    proj_kernel<<<dim3(ROWS/16, 3), 256, 0, stream>>>(vec, Wqt, Wkt, Wvt, Qbf, Kbf, Vt);
    attn_kernel<<<dim3(SEQ/64, BATCH*NH), 256, 0, stream>>>(Qbf, Kbf, Vt, rb);
    out_kernel<<<dim3(ROWS/32, 4), 256, 0, stream>>>(rb, Wot, out);
}

// Round 16
// 48.565 us; speedup vs baseline: 1.4144x; 1.2229x over previous
//
#include <hip/hip_runtime.h>
#include <hip/hip_bf16.h>

#define UNIF 128
#define NH   8
#define HD   16
#define BATCH 4
#define SEQ  2048
#define ROWS (BATCH*SEQ)   // 8192

typedef __attribute__((ext_vector_type(8)))  short bf16x8;
typedef __attribute__((ext_vector_type(16))) float f32x16;
typedef __attribute__((ext_vector_type(4)))  float f32x4;
typedef __attribute__((ext_vector_type(4)))  unsigned uint32x4;
typedef __attribute__((ext_vector_type(2)))  unsigned uint2v;

// round-to-nearest-even f32 -> bf16 (finite inputs)
static __device__ __forceinline__ unsigned f2bf(float x) {
    unsigned u = __builtin_bit_cast(unsigned, x);
    return (u + 0x7fffu + ((u >> 16) & 1u)) >> 16;
}
static __device__ __forceinline__ unsigned pkbf(float a, float b) {
    return f2bf(a) | (f2bf(b) << 16);
}
static __device__ __forceinline__ unsigned short bfs(float x) {
    return (unsigned short)f2bf(x);
}
// HW packed f32x2 -> bf16x2, 1 VALU op
static __device__ __forceinline__ unsigned cvtpk(float a, float b) {
    unsigned r;
    asm("v_cvt_pk_bf16_f32 %0, %1, %2" : "=v"(r) : "v"(a), "v"(b));
    return r;
}
// verified-good builtin (round 6): both outputs consumed explicitly
static __device__ __forceinline__ void plswap(unsigned &a, unsigned &b) {
    uint2v r = __builtin_amdgcn_permlane32_swap(a, b, false, false);
    a = r[0]; b = r[1];
}
// 8 fp32 -> bf16x8 fragment (4 cvt_pk)
static __device__ __forceinline__ bf16x8 ld8f(const float* p) {
    const float4 x = *(const float4*)p;
    const float4 y = *(const float4*)(p + 4);
    uint32x4 u = { cvtpk(x.x, x.y), cvtpk(x.z, x.w),
                   cvtpk(y.x, y.y), cvtpk(y.z, y.w) };
    return __builtin_bit_cast(bf16x8, u);
}

// ---------------- Kernel 0: prep — W transposes only (32 blocks) ------------
// Wqt/Wkt/Wvt[c][k] (c=h*16+d, Q pre-scaled by 0.25*log2e); Wot[o][c].
__global__ __launch_bounds__(256) void prep_kernel(
    const float* __restrict__ Wq, const float* __restrict__ Wk,
    const float* __restrict__ Wv, const float* __restrict__ Wo,
    unsigned short* __restrict__ Wqt, unsigned short* __restrict__ Wkt,
    unsigned short* __restrict__ Wvt, unsigned short* __restrict__ Wot)
{
    const int m  = blockIdx.x >> 3;
    const int r0 = (blockIdx.x & 7) * 16;
    unsigned short* dst = (m==0)?Wqt:(m==1)?Wkt:(m==2)?Wvt:Wot;
    const float qsc = 0.25f * 1.4426950408889634f;   // 1/sqrt(16)*log2e into Wq
    for (int t = threadIdx.x; t < 16*UNIF; t += 256) {
        const int r = r0 + (t >> 7), s = t & 127;
        float val;
        if (m == 0)      val = Wq[s*UNIF + r] * qsc;
        else if (m == 1) val = Wk[s*UNIF + r];
        else if (m == 2) val = Wv[s*UNIF + (r & 15)*NH + (r >> 4)];
        else             val = Wo[((s & 15)*NH + (s >> 4))*UNIF + r];
        dst[r*UNIF + s] = bfs(val);
    }
}

// ---------------- Kernel A: QKV projection, pure MFMA, fp32 vec inline ------
__global__ __launch_bounds__(256) void proj_kernel(
    const float* __restrict__ vec,  const unsigned short* __restrict__ Wqt,
    const unsigned short* __restrict__ Wkt, const unsigned short* __restrict__ Wvt,
    unsigned short* __restrict__ Qbf, unsigned short* __restrict__ Kbf,
    unsigned short* __restrict__ Vt)
{
    const int sel  = blockIdx.y;
    const int row0 = blockIdx.x * 32;
    const int b    = row0 >> 11;
    const int n0   = row0 & (SEQ-1);
    const int lane = threadIdx.x & 63;
    const int w    = threadIdx.x >> 6;
    const int l15  = lane & 15, g = lane >> 4;
    const f32x4 Z4 = {0.f,0.f,0.f,0.f};

    if (sel < 2) {
        const unsigned short* Wt = sel ? Wkt : Wqt;
        unsigned short* dst = sel ? Kbf : Qbf;
        const int rw = row0 + (w & 1)*16;
        const int nb = rw & (SEQ-1);
        bf16x8 a[4];
        #pragma unroll
        for (int t = 0; t < 4; ++t)
            a[t] = ld8f(vec + (size_t)(rw + l15)*UNIF + 32*t + 8*g);
        const int c0 = (w >> 1) * 64;
        #pragma unroll
        for (int j = 0; j < 4; ++j) {
            const int ctile = c0 + 16*j;
            f32x4 acc = Z4;
            #pragma unroll
            for (int t = 0; t < 4; ++t) {
                const bf16x8 bfr = *(const bf16x8*)(Wt + (size_t)(ctile + l15)*UNIF + 32*t + 8*g);
                acc = __builtin_amdgcn_mfma_f32_16x16x32_bf16(a[t], bfr, acc, 0, 0, 0);
            }
            const int h = ctile >> 4;
            #pragma unroll
            for (int r = 0; r < 4; ++r)
                dst[((size_t)(b*NH + h)*SEQ + nb + 4*g + r)*HD + l15] = bfs(acc[r]);
        }
    } else {
        bf16x8 a[2][4], bb[2][4];
        #pragma unroll
        for (int j = 0; j < 2; ++j)
            #pragma unroll
            for (int t = 0; t < 4; ++t)
                a[j][t] = *(const bf16x8*)(Wvt + (size_t)(w*32 + 16*j + l15)*UNIF + 32*t + 8*g);
        #pragma unroll
        for (int u = 0; u < 2; ++u)
            #pragma unroll
            for (int t = 0; t < 4; ++t)
                bb[u][t] = ld8f(vec + (size_t)(row0 + 16*u + l15)*UNIF + 32*t + 8*g);
        #pragma unroll
        for (int j = 0; j < 2; ++j) {
            #pragma unroll
            for (int u = 0; u < 2; ++u) {
                f32x4 acc = Z4;
                #pragma unroll
                for (int t = 0; t < 4; ++t)
                    acc = __builtin_amdgcn_mfma_f32_16x16x32_bf16(a[j][t], bb[u][t], acc, 0, 0, 0);
                #pragma unroll
                for (int r = 0; r < 4; ++r) {
                    const int c = w*32 + 16*j + 4*g + r;
                    const int h = c >> 4, d = c & 15;
                    Vt[((size_t)(b*NH + h)*HD + d)*SEQ + n0 + 16*u + l15] = bfs(acc[r]);
                }
            }
        }
    }
}

// ---------------- Kernel B: MFMA attention, in-register softmax -------------
// grid (SEQ/64, 32bh), block 256 = 4 j-quarter waves; each block does TWO
// 32-row i-tiles sharing K/V loads. No-shift softmax; l via ones-rows 16/20.
// KNOWN-STABLE loop body (rounds 7/10/11/12 all passed); do not perturb.
__global__ __launch_bounds__(256, 4) void attn_kernel(
    const unsigned short* __restrict__ Qbf, const unsigned short* __restrict__ Kbf,
    const unsigned short* __restrict__ Vt, unsigned short* __restrict__ rb)
{
    __shared__ float Obuf[2][2][2][9][32];   // [itile][buf][hi][reg][i] 18 KB

    const int lane = threadIdx.x & 63;
    const int w    = threadIdx.x >> 6;    // j-quarter
    const int bh   = blockIdx.y;
    const int i0   = blockIdx.x * 64;
    const int l31  = lane & 31, hi = lane >> 5;

    const bf16x8 qA = *(const bf16x8*)(Qbf + ((size_t)bh*SEQ + i0      + l31)*HD + 8*hi);
    const bf16x8 qC = *(const bf16x8*)(Qbf + ((size_t)bh*SEQ + i0 + 32 + l31)*HD + 8*hi);
    const unsigned short* kp   = Kbf + (size_t)bh*SEQ*HD + ((size_t)(w*(SEQ/4) + l31))*HD + 8*hi;
    const unsigned short* vrow = Vt  + ((size_t)bh*HD + l31)*SEQ + w*(SEQ/4);  // deref only l31<16

    const unsigned ov = (l31 == 16 || l31 == 20) ? 0x3F803F80u : 0u;
    const uint32x4 ac4 = {ov, ov, ov, ov};
    const bf16x8 acst = __builtin_bit_cast(bf16x8, ac4);

    f32x16 OA = {0.f,0.f,0.f,0.f,0.f,0.f,0.f,0.f,0.f,0.f,0.f,0.f,0.f,0.f,0.f,0.f};
    f32x16 OC = OA;
    const f32x16 Zero = OA;

    auto process = [&](const bf16x8& qB, const bf16x8& kA,
                       const bf16x8& av0, const bf16x8& av1, f32x16& O) {
        f32x16 S = __builtin_amdgcn_mfma_f32_32x32x16_bf16(kA, qB, Zero, 0, 0, 0);
        unsigned W0[4], W1[4];
        #pragma unroll
        for (int c = 0; c < 4; ++c) {
            W0[c] = cvtpk(__builtin_amdgcn_exp2f(S[4*c+0]), __builtin_amdgcn_exp2f(S[4*c+1]));
            W1[c] = cvtpk(__builtin_amdgcn_exp2f(S[4*c+2]), __builtin_amdgcn_exp2f(S[4*c+3]));
        }
        plswap(W0[0], W0[1]);  plswap(W1[0], W1[1]);
        plswap(W0[2], W0[3]);  plswap(W1[2], W1[3]);
        const uint32x4 fa = {W0[0], W1[0], W0[1], W1[1]};
        const uint32x4 fb = {W0[2], W1[2], W0[3], W1[3]};
        O = __builtin_amdgcn_mfma_f32_32x32x16_bf16(av0, __builtin_bit_cast(bf16x8, fa), O, 0, 0, 0);
        O = __builtin_amdgcn_mfma_f32_32x32x16_bf16(av1, __builtin_bit_cast(bf16x8, fb), O, 0, 0, 0);
    };

    constexpr int NT = (SEQ/4)/32;   // 16 j-tiles per wave
    #pragma unroll 1
    for (int t = 0; t < NT; ++t) {
        const bf16x8 kA = *(const bf16x8*)(kp + (size_t)t*32*HD);
        bf16x8 av0 = acst, av1 = acst;
        if (l31 < 16) {
            av0 = *(const bf16x8*)(vrow + t*32 + 8*hi);
            av1 = *(const bf16x8*)(vrow + t*32 + 16 + 8*hi);
        }
        process(qA, kA, av0, av1, OA);
        process(qC, kA, av0, av1, OC);
    }

    // ---- merge 4 j-quarters per i-tile ----
    const int buf = w >> 1;
    if (w & 1) {
        #pragma unroll
        for (int r = 0; r < 9; ++r) {
            Obuf[0][buf][hi][r][l31] = OA[r];
            Obuf[1][buf][hi][r][l31] = OC[r];
        }
    }
    __syncthreads();
    if (!(w & 1)) {
        #pragma unroll
        for (int r = 0; r < 9; ++r) {
            OA[r] += Obuf[0][buf][hi][r][l31];
            OC[r] += Obuf[1][buf][hi][r][l31];
        }
        if (w == 2) {
            #pragma unroll
            for (int r = 0; r < 9; ++r) {
                Obuf[0][1][hi][r][l31] = OA[r];
                Obuf[1][1][hi][r][l31] = OC[r];
            }
        }
    }
    __syncthreads();
    if (w == 0) {
        #pragma unroll
        for (int r = 0; r < 9; ++r) {
            OA[r] += Obuf[0][1][hi][r][l31];
            OC[r] += Obuf[1][1][hi][r][l31];
        }
        const int b = bh >> 3, h = bh & 7;
        #pragma unroll
        for (int it = 0; it < 2; ++it) {
            const f32x16& O = it ? OC : OA;
            const float inv = 1.f / O[8];
            const unsigned a0 = pkbf(O[0]*inv, O[1]*inv);
            const unsigned a1 = pkbf(O[2]*inv, O[3]*inv);
            const unsigned a2 = pkbf(O[4]*inv, O[5]*inv);
            const unsigned a3 = pkbf(O[6]*inv, O[7]*inv);
            unsigned short* base = rb + ((size_t)b*SEQ + i0 + it*32 + l31)*UNIF + h*HD + hi*4;
            uint2 u01; u01.x = a0; u01.y = a1;
            uint2 u23; u23.x = a2; u23.y = a3;
            *(uint2*)(base)     = u01;
            *(uint2*)(base + 8) = u23;
        }
    }
}

// ---------------- Kernel C: output projection, pure MFMA --------------------
__global__ __launch_bounds__(256) void out_kernel(
    const unsigned short* __restrict__ rb, const unsigned short* __restrict__ Wot,
    float* __restrict__ out)
{
    const int row0 = blockIdx.x * 32;
    const int lane = threadIdx.x & 63;
    const int w    = threadIdx.x >> 6;
    const int l15  = lane & 15, g = lane >> 4;
    const int rw   = row0 + (w & 1)*16;
    const int oc   = blockIdx.y*32 + (w >> 1)*16;
    const f32x4 Z4 = {0.f,0.f,0.f,0.f};

    bf16x8 a[4];
    #pragma unroll
    for (int t = 0; t < 4; ++t)
        a[t] = *(const bf16x8*)(rb + (size_t)(rw + l15)*UNIF + 32*t + 8*g);

    f32x4 acc = Z4;
    #pragma unroll
    for (int t = 0; t < 4; ++t) {
        const bf16x8 bfr = *(const bf16x8*)(Wot + (size_t)(oc + l15)*UNIF + 32*t + 8*g);
        acc = __builtin_amdgcn_mfma_f32_16x16x32_bf16(a[t], bfr, acc, 0, 0, 0);
    }
    #pragma unroll
    for (int r = 0; r < 4; ++r)
        out[(size_t)(rw + 4*g + r)*UNIF + oc + l15] = acc[r];
}

extern "C" void kernel_launch(void* const* d_in, const int* in_sizes, int n_in,
                              void* d_out, int out_size, void* d_ws, size_t ws_size,
                              hipStream_t stream) {
    const float* Wq  = (const float*)d_in[0];
    const float* Wk  = (const float*)d_in[1];
    const float* Wv  = (const float*)d_in[2];
    const float* Wo  = (const float*)d_in[3];
    const float* vec = (const float*)d_in[4];
    float* out = (float*)d_out;

    const size_t tsz = (size_t)BATCH*NH*SEQ*HD;
    unsigned short* Wqt = (unsigned short*)d_ws;
    unsigned short* Wkt = Wqt + UNIF*UNIF;
    unsigned short* Wvt = Wkt + UNIF*UNIF;
    unsigned short* Wot = Wvt + UNIF*UNIF;
    unsigned short* Qbf = Wot + UNIF*UNIF;
    unsigned short* Kbf = Qbf + tsz;
    unsigned short* Vt  = Kbf + tsz;
    unsigned short* rb  = Vt  + tsz;

    prep_kernel<<<32, 256, 0, stream>>>(Wq, Wk, Wv, Wo, Wqt, Wkt, Wvt, Wot);
    proj_kernel<<<dim3(ROWS/32, 3), 256, 0, stream>>>(vec, Wqt, Wkt, Wvt, Qbf, Kbf, Vt);
    attn_kernel<<<dim3(SEQ/64, BATCH*NH), 256, 0, stream>>>(Qbf, Kbf, Vt, rb);
    out_kernel<<<dim3(ROWS/32, 4), 256, 0, stream>>>(rb, Wot, out);
}

// Round 17
// 47.374 us; speedup vs baseline: 1.4499x; 1.0251x over previous
//
#include <hip/hip_runtime.h>
#include <hip/hip_bf16.h>

#define UNIF 128
#define NH   8
#define HD   16
#define BATCH 4
#define SEQ  2048
#define ROWS (BATCH*SEQ)   // 8192

typedef __attribute__((ext_vector_type(8)))  short bf16x8;
typedef __attribute__((ext_vector_type(16))) float f32x16;
typedef __attribute__((ext_vector_type(4)))  float f32x4;
typedef __attribute__((ext_vector_type(4)))  unsigned uint32x4;
typedef __attribute__((ext_vector_type(2)))  unsigned uint2v;

// round-to-nearest-even f32 -> bf16 (finite inputs)
static __device__ __forceinline__ unsigned f2bf(float x) {
    unsigned u = __builtin_bit_cast(unsigned, x);
    return (u + 0x7fffu + ((u >> 16) & 1u)) >> 16;
}
static __device__ __forceinline__ unsigned pkbf(float a, float b) {
    return f2bf(a) | (f2bf(b) << 16);
}
static __device__ __forceinline__ unsigned short bfs(float x) {
    return (unsigned short)f2bf(x);
}
// HW packed f32x2 -> bf16x2, 1 VALU op
static __device__ __forceinline__ unsigned cvtpk(float a, float b) {
    unsigned r;
    asm("v_cvt_pk_bf16_f32 %0, %1, %2" : "=v"(r) : "v"(a), "v"(b));
    return r;
}
// verified-good builtin (round 6): both outputs consumed explicitly
static __device__ __forceinline__ void plswap(unsigned &a, unsigned &b) {
    uint2v r = __builtin_amdgcn_permlane32_swap(a, b, false, false);
    a = r[0]; b = r[1];
}
// 8 fp32 -> bf16x8 fragment (4 cvt_pk)
static __device__ __forceinline__ bf16x8 ld8f(const float* p) {
    const float4 x = *(const float4*)p;
    const float4 y = *(const float4*)(p + 4);
    uint32x4 u = { cvtpk(x.x, x.y), cvtpk(x.z, x.w),
                   cvtpk(y.x, y.y), cvtpk(y.z, y.w) };
    return __builtin_bit_cast(bf16x8, u);
}

// ---------------- Kernel 0: prep — W transposes only (32 blocks) ------------
__global__ __launch_bounds__(256) void prep_kernel(
    const float* __restrict__ Wq, const float* __restrict__ Wk,
    const float* __restrict__ Wv, const float* __restrict__ Wo,
    unsigned short* __restrict__ Wqt, unsigned short* __restrict__ Wkt,
    unsigned short* __restrict__ Wvt, unsigned short* __restrict__ Wot)
{
    const int m  = blockIdx.x >> 3;
    const int r0 = (blockIdx.x & 7) * 16;
    unsigned short* dst = (m==0)?Wqt:(m==1)?Wkt:(m==2)?Wvt:Wot;
    const float qsc = 0.25f * 1.4426950408889634f;   // 1/sqrt(16)*log2e into Wq
    for (int t = threadIdx.x; t < 16*UNIF; t += 256) {
        const int r = r0 + (t >> 7), s = t & 127;
        float val;
        if (m == 0)      val = Wq[s*UNIF + r] * qsc;
        else if (m == 1) val = Wk[s*UNIF + r];
        else if (m == 2) val = Wv[s*UNIF + (r & 15)*NH + (r >> 4)];
        else             val = Wo[((s & 15)*NH + (s >> 4))*UNIF + r];
        dst[r*UNIF + s] = bfs(val);
    }
}

// ---------------- Kernel A: QKV projection, pure MFMA, fp32 vec inline ------
__global__ __launch_bounds__(256) void proj_kernel(
    const float* __restrict__ vec,  const unsigned short* __restrict__ Wqt,
    const unsigned short* __restrict__ Wkt, const unsigned short* __restrict__ Wvt,
    unsigned short* __restrict__ Qbf, unsigned short* __restrict__ Kbf,
    unsigned short* __restrict__ Vt)
{
    const int sel  = blockIdx.y;
    const int row0 = blockIdx.x * 32;
    const int b    = row0 >> 11;
    const int n0   = row0 & (SEQ-1);
    const int lane = threadIdx.x & 63;
    const int w    = threadIdx.x >> 6;
    const int l15  = lane & 15, g = lane >> 4;
    const f32x4 Z4 = {0.f,0.f,0.f,0.f};

    if (sel < 2) {
        const unsigned short* Wt = sel ? Wkt : Wqt;
        unsigned short* dst = sel ? Kbf : Qbf;
        const int rw = row0 + (w & 1)*16;
        const int nb = rw & (SEQ-1);
        bf16x8 a[4];
        #pragma unroll
        for (int t = 0; t < 4; ++t)
            a[t] = ld8f(vec + (size_t)(rw + l15)*UNIF + 32*t + 8*g);
        const int c0 = (w >> 1) * 64;
        #pragma unroll
        for (int j = 0; j < 4; ++j) {
            const int ctile = c0 + 16*j;
            f32x4 acc = Z4;
            #pragma unroll
            for (int t = 0; t < 4; ++t) {
                const bf16x8 bfr = *(const bf16x8*)(Wt + (size_t)(ctile + l15)*UNIF + 32*t + 8*g);
                acc = __builtin_amdgcn_mfma_f32_16x16x32_bf16(a[t], bfr, acc, 0, 0, 0);
            }
            const int h = ctile >> 4;
            #pragma unroll
            for (int r = 0; r < 4; ++r)
                dst[((size_t)(b*NH + h)*SEQ + nb + 4*g + r)*HD + l15] = bfs(acc[r]);
        }
    } else {
        bf16x8 a[2][4], bb[2][4];
        #pragma unroll
        for (int j = 0; j < 2; ++j)
            #pragma unroll
            for (int t = 0; t < 4; ++t)
                a[j][t] = *(const bf16x8*)(Wvt + (size_t)(w*32 + 16*j + l15)*UNIF + 32*t + 8*g);
        #pragma unroll
        for (int u = 0; u < 2; ++u)
            #pragma unroll
            for (int t = 0; t < 4; ++t)
                bb[u][t] = ld8f(vec + (size_t)(row0 + 16*u + l15)*UNIF + 32*t + 8*g);
        #pragma unroll
        for (int j = 0; j < 2; ++j) {
            #pragma unroll
            for (int u = 0; u < 2; ++u) {
                f32x4 acc = Z4;
                #pragma unroll
                for (int t = 0; t < 4; ++t)
                    acc = __builtin_amdgcn_mfma_f32_16x16x32_bf16(a[j][t], bb[u][t], acc, 0, 0, 0);
                #pragma unroll
                for (int r = 0; r < 4; ++r) {
                    const int c = w*32 + 16*j + 4*g + r;
                    const int h = c >> 4, d = c & 15;
                    Vt[((size_t)(b*NH + h)*HD + d)*SEQ + n0 + 16*u + l15] = bfs(acc[r]);
                }
            }
        }
    }
}

// ---------------- Kernel B: MFMA attention (stable body + XCD swizzle) ------
// 1D grid 1024; ib = (it<<3) | (bh&7) | ((bh>>3)<<8)  [bijective]. With
// round-robin dispatch XCD = ib%8 = bh&7, so each XCD's co-resident blocks
// cover exactly 4 bh = 1 MB K/V -> fits 4 MB XCD L2 (was 8 MB thrash).
// Loop body is byte-identical to the verified round-7/10/16 kernel.
__global__ __launch_bounds__(256, 4) void attn_kernel(
    const unsigned short* __restrict__ Qbf, const unsigned short* __restrict__ Kbf,
    const unsigned short* __restrict__ Vt, unsigned short* __restrict__ rb)
{
    __shared__ float Obuf[2][2][2][9][32];   // [itile][buf][hi][reg][i] 18 KB

    const int lane = threadIdx.x & 63;
    const int w    = threadIdx.x >> 6;    // j-quarter
    const int ib   = blockIdx.x;
    const int bh   = (ib & 7) | ((ib >> 8) << 3);
    const int i0   = ((ib >> 3) & 31) * 64;
    const int l31  = lane & 31, hi = lane >> 5;

    const bf16x8 qA = *(const bf16x8*)(Qbf + ((size_t)bh*SEQ + i0      + l31)*HD + 8*hi);
    const bf16x8 qC = *(const bf16x8*)(Qbf + ((size_t)bh*SEQ + i0 + 32 + l31)*HD + 8*hi);
    const unsigned short* kp   = Kbf + (size_t)bh*SEQ*HD + ((size_t)(w*(SEQ/4) + l31))*HD + 8*hi;
    const unsigned short* vrow = Vt  + ((size_t)bh*HD + l31)*SEQ + w*(SEQ/4);  // deref only l31<16

    const unsigned ov = (l31 == 16 || l31 == 20) ? 0x3F803F80u : 0u;
    const uint32x4 ac4 = {ov, ov, ov, ov};
    const bf16x8 acst = __builtin_bit_cast(bf16x8, ac4);

    f32x16 OA = {0.f,0.f,0.f,0.f,0.f,0.f,0.f,0.f,0.f,0.f,0.f,0.f,0.f,0.f,0.f,0.f};
    f32x16 OC = OA;
    const f32x16 Zero = OA;

    auto process = [&](const bf16x8& qB, const bf16x8& kA,
                       const bf16x8& av0, const bf16x8& av1, f32x16& O) {
        f32x16 S = __builtin_amdgcn_mfma_f32_32x32x16_bf16(kA, qB, Zero, 0, 0, 0);
        unsigned W0[4], W1[4];
        #pragma unroll
        for (int c = 0; c < 4; ++c) {
            W0[c] = cvtpk(__builtin_amdgcn_exp2f(S[4*c+0]), __builtin_amdgcn_exp2f(S[4*c+1]));
            W1[c] = cvtpk(__builtin_amdgcn_exp2f(S[4*c+2]), __builtin_amdgcn_exp2f(S[4*c+3]));
        }
        plswap(W0[0], W0[1]);  plswap(W1[0], W1[1]);
        plswap(W0[2], W0[3]);  plswap(W1[2], W1[3]);
        const uint32x4 fa = {W0[0], W1[0], W0[1], W1[1]};
        const uint32x4 fb = {W0[2], W1[2], W0[3], W1[3]};
        O = __builtin_amdgcn_mfma_f32_32x32x16_bf16(av0, __builtin_bit_cast(bf16x8, fa), O, 0, 0, 0);
        O = __builtin_amdgcn_mfma_f32_32x32x16_bf16(av1, __builtin_bit_cast(bf16x8, fb), O, 0, 0, 0);
    };

    constexpr int NT = (SEQ/4)/32;   // 16 j-tiles per wave
    #pragma unroll 1
    for (int t = 0; t < NT; ++t) {
        const bf16x8 kA = *(const bf16x8*)(kp + (size_t)t*32*HD);
        bf16x8 av0 = acst, av1 = acst;
        if (l31 < 16) {
            av0 = *(const bf16x8*)(vrow + t*32 + 8*hi);
            av1 = *(const bf16x8*)(vrow + t*32 + 16 + 8*hi);
        }
        process(qA, kA, av0, av1, OA);
        process(qC, kA, av0, av1, OC);
    }

    // ---- merge 4 j-quarters per i-tile ----
    const int buf = w >> 1;
    if (w & 1) {
        #pragma unroll
        for (int r = 0; r < 9; ++r) {
            Obuf[0][buf][hi][r][l31] = OA[r];
            Obuf[1][buf][hi][r][l31] = OC[r];
        }
    }
    __syncthreads();
    if (!(w & 1)) {
        #pragma unroll
        for (int r = 0; r < 9; ++r) {
            OA[r] += Obuf[0][buf][hi][r][l31];
            OC[r] += Obuf[1][buf][hi][r][l31];
        }
        if (w == 2) {
            #pragma unroll
            for (int r = 0; r < 9; ++r) {
                Obuf[0][1][hi][r][l31] = OA[r];
                Obuf[1][1][hi][r][l31] = OC[r];
            }
        }
    }
    __syncthreads();
    if (w == 0) {
        #pragma unroll
        for (int r = 0; r < 9; ++r) {
            OA[r] += Obuf[0][1][hi][r][l31];
            OC[r] += Obuf[1][1][hi][r][l31];
        }
        const int b = bh >> 3, h = bh & 7;
        #pragma unroll
        for (int it = 0; it < 2; ++it) {
            const f32x16& O = it ? OC : OA;
            const float inv = 1.f / O[8];
            const unsigned a0 = pkbf(O[0]*inv, O[1]*inv);
            const unsigned a1 = pkbf(O[2]*inv, O[3]*inv);
            const unsigned a2 = pkbf(O[4]*inv, O[5]*inv);
            const unsigned a3 = pkbf(O[6]*inv, O[7]*inv);
            unsigned short* base = rb + ((size_t)b*SEQ + i0 + it*32 + l31)*UNIF + h*HD + hi*4;
            uint2 u01; u01.x = a0; u01.y = a1;
            uint2 u23; u23.x = a2; u23.y = a3;
            *(uint2*)(base)     = u01;
            *(uint2*)(base + 8) = u23;
        }
    }
}

// ---------------- Kernel C: output projection, pure MFMA --------------------
__global__ __launch_bounds__(256) void out_kernel(
    const unsigned short* __restrict__ rb, const unsigned short* __restrict__ Wot,
    float* __restrict__ out)
{
    const int row0 = blockIdx.x * 32;
    const int lane = threadIdx.x & 63;
    const int w    = threadIdx.x >> 6;
    const int l15  = lane & 15, g = lane >> 4;
    const int rw   = row0 + (w & 1)*16;
    const int oc   = blockIdx.y*32 + (w >> 1)*16;
    const f32x4 Z4 = {0.f,0.f,0.f,0.f};

    bf16x8 a[4];
    #pragma unroll
    for (int t = 0; t < 4; ++t)
        a[t] = *(const bf16x8*)(rb + (size_t)(rw + l15)*UNIF + 32*t + 8*g);

    f32x4 acc = Z4;
    #pragma unroll
    for (int t = 0; t < 4; ++t) {
        const bf16x8 bfr = *(const bf16x8*)(Wot + (size_t)(oc + l15)*UNIF + 32*t + 8*g);
        acc = __builtin_amdgcn_mfma_f32_16x16x32_bf16(a[t], bfr, acc, 0, 0, 0);
    }
    #pragma unroll
    for (int r = 0; r < 4; ++r)
        out[(size_t)(rw + 4*g + r)*UNIF + oc + l15] = acc[r];
}

extern "C" void kernel_launch(void* const* d_in, const int* in_sizes, int n_in,
                              void* d_out, int out_size, void* d_ws, size_t ws_size,
                              hipStream_t stream) {
    const float* Wq  = (const float*)d_in[0];
    const float* Wk  = (const float*)d_in[1];
    const float* Wv  = (const float*)d_in[2];
    const float* Wo  = (const float*)d_in[3];
    const float* vec = (const float*)d_in[4];
    float* out = (float*)d_out;

    const size_t tsz = (size_t)BATCH*NH*SEQ*HD;
    unsigned short* Wqt = (unsigned short*)d_ws;
    unsigned short* Wkt = Wqt + UNIF*UNIF;
    unsigned short* Wvt = Wkt + UNIF*UNIF;
    unsigned short* Wot = Wvt + UNIF*UNIF;
    unsigned short* Qbf = Wot + UNIF*UNIF;
    unsigned short* Kbf = Qbf + tsz;
    unsigned short* Vt  = Kbf + tsz;
    unsigned short* rb  = Vt  + tsz;

    prep_kernel<<<32, 256, 0, stream>>>(Wq, Wk, Wv, Wo, Wqt, Wkt, Wvt, Wot);
    proj_kernel<<<dim3(ROWS/32, 3), 256, 0, stream>>>(vec, Wqt, Wkt, Wvt, Qbf, Kbf, Vt);
    attn_kernel<<<1024, 256, 0, stream>>>(Qbf, Kbf, Vt, rb);
    out_kernel<<<dim3(ROWS/32, 4), 256, 0, stream>>>(rb, Wot, out);
}